// Round 13
// baseline (267.422 us; speedup 1.0000x reference)
//
#include <hip/hip_runtime.h>
#include <math.h>

#define NTOK 1024
#define DMODEL 1024
#define BATCH 4

typedef __bf16 bf16x8 __attribute__((ext_vector_type(8)));
typedef float  f32x4  __attribute__((ext_vector_type(4)));
typedef unsigned short ushort_t;
typedef unsigned short us8 __attribute__((ext_vector_type(8)));

static __device__ __forceinline__ ushort_t f2bf(float f) {
  unsigned u = __float_as_uint(f);
  u += 0x7fffu + ((u >> 16) & 1u);   // RNE (inputs are finite)
  return (ushort_t)(u >> 16);
}
static __device__ __forceinline__ float bf2f(ushort_t v) {
  return __uint_as_float(((unsigned)v) << 16);
}

// tanh-form gelu via sigmoid: gelu(v) = v * sigmoid(1.5957691·(v + 0.044715·v^3))
static __device__ __forceinline__ float fast_gelu(float v) {
  const float u = 1.5957691216057308f * (v + 0.044715f * v * v * v);
  return v / (1.f + __expf(-u));
}

static __device__ __forceinline__ void gld16(void* lds, const void* g) {
  __builtin_amdgcn_global_load_lds(
      (const __attribute__((address_space(1))) void*)g,
      (__attribute__((address_space(3))) void*)lds, 16, 0, 0);
}

// ---- merged prep: LN1 (blocks [0,4096)) + weight transposes ([4096,12288)) ----
__global__ __launch_bounds__(256) void prep_kernel(
    const float* __restrict__ x, const float* __restrict__ g,
    const float* __restrict__ b, ushort_t* __restrict__ out,
    const float* __restrict__ W1, ushort_t* __restrict__ W1t,
    const float* __restrict__ W2, ushort_t* __restrict__ W2t)
{
  if (blockIdx.x < 4096) {
    const int row = blockIdx.x;
    const int tid = threadIdx.x;
    const float* xr = x + (size_t)row * DMODEL;
    float4 v = *(const float4*)(xr + 4 * tid);
    float s1 = v.x + v.y + v.z + v.w;
    float s2 = v.x * v.x + v.y * v.y + v.z * v.z + v.w * v.w;
#pragma unroll
    for (int d = 1; d < 64; d <<= 1) { s1 += __shfl_xor(s1, d); s2 += __shfl_xor(s2, d); }
    __shared__ float red[10];
    const int wid = tid >> 6;
    if ((tid & 63) == 0) { red[wid] = s1; red[4 + wid] = s2; }
    __syncthreads();
    if (tid == 0) {
      float a = red[0] + red[1] + red[2] + red[3];
      float c = red[4] + red[5] + red[6] + red[7];
      float mu = a / (float)DMODEL;
      float var = c / (float)DMODEL - mu * mu;
      red[8] = mu; red[9] = rsqrtf(var + 1e-5f);
    }
    __syncthreads();
    const float mu = red[8], inv = red[9];
    float4 gg = *(const float4*)(g + 4 * tid);
    float4 bb = *(const float4*)(b + 4 * tid);
    ushort4 o;
    o.x = f2bf((v.x - mu) * inv * gg.x + bb.x);
    o.y = f2bf((v.y - mu) * inv * gg.y + bb.y);
    o.z = f2bf((v.z - mu) * inv * gg.z + bb.z);
    o.w = f2bf((v.w - mu) * inv * gg.w + bb.w);
    *(ushort4*)(out + (size_t)row * DMODEL + 4 * tid) = o;
  } else {
    __shared__ float t[32][33];
    int id = blockIdx.x - 4096;
    const float* W; ushort_t* Wt; int K, N, bx, by;
    if (id < 4096) { W = W1; Wt = W1t; K = 1024; N = 4096; bx = id & 127; by = id >> 7; }
    else { id -= 4096; W = W2; Wt = W2t; K = 4096; N = 1024; bx = id & 31; by = id >> 5; }
    const int kb = by * 32, nb = bx * 32;
    const int c = threadIdx.x & 31, r0 = threadIdx.x >> 5;
#pragma unroll
    for (int r = r0; r < 32; r += 8)
      t[r][c] = W[(size_t)(kb + r) * N + nb + c];
    __syncthreads();
#pragma unroll
    for (int r = r0; r < 32; r += 8)
      Wt[(size_t)(nb + r) * K + kb + c] = f2bf(t[c][r]);
  }
}

// ---- Sparse gated attention (bf16 K/V, 2 queries/block) + residual + LN2 ---
__global__ __launch_bounds__(256) void attn_kernel(
    const float* __restrict__ x, const ushort_t* __restrict__ normedB,
    const int* __restrict__ adj, const float* __restrict__ stoich,
    const float* __restrict__ gW, const float* __restrict__ gb,
    const float* __restrict__ ln2g, const float* __restrict__ ln2b,
    const float* __restrict__ b2,
    float* __restrict__ outbase, ushort_t* __restrict__ normed2)
{
  __shared__ int   neigh[2][NTOK];
  __shared__ float gateS[2][NTOK];
  __shared__ int   cntS[2];
  __shared__ float red[2][6];

  const int tid = threadIdx.x;
  const int sub = tid >> 7;
  const int t   = tid & 127;
  const int row = blockIdx.x * 2 + sub;   // [0, 4096)
  const int b   = row >> 10;

  if (tid < 2) cntS[tid] = 0;
  __syncthreads();
  const int* arow = adj + (size_t)row * NTOK;
  {
    int4 a4 = ((const int4*)arow)[t];
    int k0 = 4 * t;
    if (a4.x > 0) { int p = atomicAdd(&cntS[sub], 1); neigh[sub][p] = k0; }
    if (a4.y > 0) { int p = atomicAdd(&cntS[sub], 1); neigh[sub][p] = k0 + 1; }
    if (a4.z > 0) { int p = atomicAdd(&cntS[sub], 1); neigh[sub][p] = k0 + 2; }
    if (a4.w > 0) { int p = atomicAdd(&cntS[sub], 1); neigh[sub][p] = k0 + 3; }
    a4 = ((const int4*)arow)[t + 128];
    k0 = 4 * (t + 128);
    if (a4.x > 0) { int p = atomicAdd(&cntS[sub], 1); neigh[sub][p] = k0; }
    if (a4.y > 0) { int p = atomicAdd(&cntS[sub], 1); neigh[sub][p] = k0 + 1; }
    if (a4.z > 0) { int p = atomicAdd(&cntS[sub], 1); neigh[sub][p] = k0 + 2; }
    if (a4.w > 0) { int p = atomicAdd(&cntS[sub], 1); neigh[sub][p] = k0 + 3; }
  }
  __syncthreads();
  const int cnt = cntS[sub];

  const float st = stoich[row];
  for (int i = t; i < cnt; i += 128) {
    int k = neigh[sub][i];
    gateS[sub][i] = 1.f / (1.f + __expf(-fmaf(st, gW[k], gb[k])));
  }
  __syncthreads();

  const ushort_t* nbB = normedB + (size_t)b * NTOK * DMODEL;
  const int d0 = 8 * t;
  us8 qu = *(const us8*)(nbB + (size_t)(row & 1023) * DMODEL + d0);
  float qv[8];
#pragma unroll
  for (int j = 0; j < 8; ++j) qv[j] = bf2f(qu[j]);
  const float scale = 0.08838834764831845f;  // 1/sqrt(128)

  float lsum = 0.f;
  float o[8] = {0.f, 0.f, 0.f, 0.f, 0.f, 0.f, 0.f, 0.f};

  for (int i0 = 0; i0 < cnt; i0 += 8) {
    us8 ku[8]; float w8[8];
#pragma unroll
    for (int u = 0; u < 8; ++u) {
      const int i = i0 + u;
      const int ii = (i < cnt) ? i : 0;
      ku[u] = *(const us8*)(nbB + (size_t)neigh[sub][ii] * DMODEL + d0);
      w8[u] = gateS[sub][ii];
    }
#pragma unroll
    for (int u = 0; u < 8; ++u) {
      float p = 0.f;
#pragma unroll
      for (int j = 0; j < 8; ++j) p = fmaf(bf2f(ku[u][j]), qv[j], p);
      p += __shfl_xor(p, 1); p += __shfl_xor(p, 2);
      p += __shfl_xor(p, 4); p += __shfl_xor(p, 8);   // 16-lane head reduce
      w8[u] *= p * scale;
    }
#pragma unroll
    for (int u = 0; u < 8; ++u)
      w8[u] = (i0 + u < cnt) ? __expf(w8[u]) : 0.f;
#pragma unroll
    for (int u = 0; u < 8; ++u) {
      lsum += w8[u];
#pragma unroll
      for (int j = 0; j < 8; ++j) o[j] = fmaf(w8[u], bf2f(ku[u][j]), o[j]);
    }
  }
  const float pinv = 1.f / lsum;

  const float* xr = x + (size_t)row * DMODEL + d0;
  const float4 xa = *(const float4*)(xr);
  const float4 xb = *(const float4*)(xr + 4);
  float r[8];
  r[0] = xa.x + o[0] * pinv; r[1] = xa.y + o[1] * pinv;
  r[2] = xa.z + o[2] * pinv; r[3] = xa.w + o[3] * pinv;
  r[4] = xb.x + o[4] * pinv; r[5] = xb.y + o[5] * pinv;
  r[6] = xb.z + o[6] * pinv; r[7] = xb.w + o[7] * pinv;

  const float4 ba = *(const float4*)(b2 + d0);
  const float4 bbv = *(const float4*)(b2 + d0 + 4);
  float4 oa, ob;
  oa.x = r[0] + ba.x;  oa.y = r[1] + ba.y;  oa.z = r[2] + ba.z;  oa.w = r[3] + ba.w;
  ob.x = r[4] + bbv.x; ob.y = r[5] + bbv.y; ob.z = r[6] + bbv.z; ob.w = r[7] + bbv.w;
  float* obp = outbase + (size_t)row * DMODEL + d0;
  *(float4*)(obp) = oa;
  *(float4*)(obp + 4) = ob;

  float s1 = 0.f, s2 = 0.f;
#pragma unroll
  for (int j = 0; j < 8; ++j) { s1 += r[j]; s2 += r[j] * r[j]; }
#pragma unroll
  for (int d = 1; d < 64; d <<= 1) { s1 += __shfl_xor(s1, d); s2 += __shfl_xor(s2, d); }
  const int wsub = (tid >> 6) & 1;
  if ((tid & 63) == 0) { red[sub][wsub] = s1; red[sub][2 + wsub] = s2; }
  __syncthreads();
  if ((tid & 127) == 0) {
    float a = red[sub][0] + red[sub][1];
    float c = red[sub][2] + red[sub][3];
    float mu = a / (float)DMODEL;
    float var = c / (float)DMODEL - mu * mu;
    red[sub][4] = mu; red[sub][5] = rsqrtf(var + 1e-5f);
  }
  __syncthreads();
  const float mu = red[sub][4], inv = red[sub][5];
  const float4 ga = *(const float4*)(ln2g + d0);
  const float4 gbv = *(const float4*)(ln2g + d0 + 4);
  const float4 la = *(const float4*)(ln2b + d0);
  const float4 lb = *(const float4*)(ln2b + d0 + 4);
  const float gg[8] = {ga.x, ga.y, ga.z, ga.w, gbv.x, gbv.y, gbv.z, gbv.w};
  const float ll[8] = {la.x, la.y, la.z, la.w, lb.x, lb.y, lb.z, lb.w};
  us8 pk;
#pragma unroll
  for (int j = 0; j < 8; ++j) pk[j] = f2bf((r[j] - mu) * inv * gg[j] + ll[j]);
  *(us8*)(normed2 + (size_t)row * DMODEL + d0) = pk;
}

// ------- GEMM1 v3: 128x128 tile, 8 waves, 2 blocks/CU, stage-early/vmcnt(4) -
// r12 post-mortem: 256^2/1-block/CU gemm1 = 89us, MfmaUtil 15%, occ 21% —
// all pipes idle; intra-block pipelining can't replace TLP (m114). This is a
// clone of the r12-HARNESS-PASSED gemm2 v3 kernel shape (128^2, 512 thr,
// acc[4][2], 64KB LDS, STAGE4/vmcnt(4)/2-barrier, verified swizzle) with the
// r2-proven grid decode (1024 blocks = 32bm x 32bn, XCD-swizzled) and the
// gelu+bias bf16 epilogue. 64KB LDS -> 2 blocks/CU resident = 16 waves/CU.
__global__ __launch_bounds__(512, 2) void gemm1_pipe(
    const ushort_t* __restrict__ A, const ushort_t* __restrict__ Bt,
    const float* __restrict__ bias, ushort_t* __restrict__ Cout,
    int M, int N, int K)
{
  __shared__ __align__(16) ushort_t As[2][128 * 64];
  __shared__ __align__(16) ushort_t Bs[2][128 * 64];

  const int id = blockIdx.x;
  const int xcd = id & 7, slot = id >> 3;        // slot 0..127
  const int bm = (xcd * 4 + (slot & 3)) * 128;   // 32 bm groups
  const int bn = (slot >> 2) * 128;              // 32 bn groups

  const int tid = threadIdx.x;                   // 0..511
  const int l = tid & 63;
  const int wid = tid >> 6;                      // 8 waves: 2(M) x 4(N)
  const int wrow = (wid >> 2) * 64;
  const int wcol = (wid & 3) * 32;

  const int sr = tid >> 3;                       // 0..63 within chunk
  const int sg = tid & 7;
  const int gsrc = ((sg ^ (sr & 7)) << 3);       // inverse-swizzled source granule
  const ushort_t* Ag = A  + (size_t)(bm + sr) * K + gsrc;
  const ushort_t* Bg = Bt + (size_t)(bn + sr) * K + gsrc;
  const int dst = tid * 8;

  const int quad = l >> 4, lrow = l & 15;
  const int swz = lrow & 7;
  const int gx0 = ((quad ^ swz) << 3);
  const int gx1 = (((quad + 4) ^ swz) << 3);

  f32x4 acc[4][2] = {};

#define STAGE4(buf, kb)                                                        \
  gld16(&As[buf][dst],        Ag + (kb));                                      \
  gld16(&As[buf][4096 + dst], Ag + (size_t)64 * K + (kb));                     \
  gld16(&Bs[buf][dst],        Bg + (kb));                                      \
  gld16(&Bs[buf][4096 + dst], Bg + (size_t)64 * K + (kb));

#define HALFK(buf, GX)                                                         \
  {                                                                            \
    bf16x8 af[4], bfv[2];                                                      \
    _Pragma("unroll")                                                          \
    for (int i = 0; i < 4; ++i)                                                \
      af[i] = *(const bf16x8*)(&As[buf][(wrow + i * 16 + lrow) * 64 + (GX)]);  \
    _Pragma("unroll")                                                          \
    for (int j = 0; j < 2; ++j)                                                \
      bfv[j] = *(const bf16x8*)(&Bs[buf][(wcol + j * 16 + lrow) * 64 + (GX)]); \
    __builtin_amdgcn_s_setprio(1);                                             \
    _Pragma("unroll")                                                          \
    for (int i = 0; i < 4; ++i)                                                \
      _Pragma("unroll")                                                        \
      for (int j = 0; j < 2; ++j)                                              \
        acc[i][j] = __builtin_amdgcn_mfma_f32_16x16x32_bf16(                   \
            af[i], bfv[j], acc[i][j], 0, 0, 0);                                \
    __builtin_amdgcn_s_setprio(0);                                             \
  }

  STAGE4(0, 0);

  const int NTK = K >> 6;                        // 16 K-tiles
#pragma unroll 1
  for (int t = 0; t < NTK - 1; ++t) {
    const int cb = t & 1, nb = cb ^ 1;
    STAGE4(nb, (t + 1) << 6);
    asm volatile("s_waitcnt vmcnt(4)" ::: "memory");
    __builtin_amdgcn_s_barrier();
    __builtin_amdgcn_sched_barrier(0);
    HALFK(cb, gx0);
    HALFK(cb, gx1);
    __builtin_amdgcn_s_barrier();
  }
  {
    const int cb = (NTK - 1) & 1;
    asm volatile("s_waitcnt vmcnt(0)" ::: "memory");
    __builtin_amdgcn_s_barrier();
    __builtin_amdgcn_sched_barrier(0);
    HALFK(cb, gx0);
    HALFK(cb, gx1);
  }
#undef STAGE4
#undef HALFK

  // epilogue: gelu(acc + bias) -> bf16
#pragma unroll
  for (int i = 0; i < 4; ++i) {
    const int row0 = bm + wrow + 16 * i + quad * 4;
#pragma unroll
    for (int j = 0; j < 2; ++j) {
      const int col = bn + wcol + 16 * j + lrow;
      const float bi = bias[col];
#pragma unroll
      for (int r = 0; r < 4; ++r)
        Cout[(size_t)(row0 + r) * N + col] = f2bf(fast_gelu(acc[i][j][r] + bi));
    }
  }
}

// ------- GEMM2 v3: 128x128 tile, 8 waves, split-K=1, NO atomics -------------
// r12: harness-passed; inferred ~38us (off top-5). Unchanged.
__global__ __launch_bounds__(512, 2) void gemm2_pipe(
    const ushort_t* __restrict__ A, const ushort_t* __restrict__ Bt,
    float* __restrict__ Cout, int M, int N, int K)
{
  __shared__ __align__(16) ushort_t As[2][128 * 64];
  __shared__ __align__(16) ushort_t Bs[2][128 * 64];

  const int id = blockIdx.x;
  const int xcd = id & 7, slot = id >> 3;        // slot 0..31
  const int bm = (xcd * 4 + (slot & 3)) * 128;   // 32 bm groups
  const int bn = (slot >> 2) * 128;              // 8 bn groups

  const int tid = threadIdx.x;                   // 0..511
  const int l = tid & 63;
  const int wid = tid >> 6;                      // 8 waves: 2(M) x 4(N)
  const int wrow = (wid >> 2) * 64;
  const int wcol = (wid & 3) * 32;

  const int sr = tid >> 3;                       // 0..63 within chunk
  const int sg = tid & 7;
  const int gsrc = ((sg ^ (sr & 7)) << 3);
  const ushort_t* Ag = A  + (size_t)(bm + sr) * K + gsrc;
  const ushort_t* Bg = Bt + (size_t)(bn + sr) * K + gsrc;
  const int dst = tid * 8;

  const int quad = l >> 4, lrow = l & 15;
  const int swz = lrow & 7;
  const int gx0 = ((quad ^ swz) << 3);
  const int gx1 = (((quad + 4) ^ swz) << 3);

  f32x4 acc[4][2] = {};

#define STAGE4(buf, kb)                                                        \
  gld16(&As[buf][dst],        Ag + (kb));                                      \
  gld16(&As[buf][4096 + dst], Ag + (size_t)64 * K + (kb));                     \
  gld16(&Bs[buf][dst],        Bg + (kb));                                      \
  gld16(&Bs[buf][4096 + dst], Bg + (size_t)64 * K + (kb));

#define HALFK(buf, GX)                                                         \
  {                                                                            \
    bf16x8 af[4], bfv[2];                                                      \
    _Pragma("unroll")                                                          \
    for (int i = 0; i < 4; ++i)                                                \
      af[i] = *(const bf16x8*)(&As[buf][(wrow + i * 16 + lrow) * 64 + (GX)]);  \
    _Pragma("unroll")                                                          \
    for (int j = 0; j < 2; ++j)                                                \
      bfv[j] = *(const bf16x8*)(&Bs[buf][(wcol + j * 16 + lrow) * 64 + (GX)]); \
    __builtin_amdgcn_s_setprio(1);                                             \
    _Pragma("unroll")                                                          \
    for (int i = 0; i < 4; ++i)                                                \
      _Pragma("unroll")                                                        \
      for (int j = 0; j < 2; ++j)                                              \
        acc[i][j] = __builtin_amdgcn_mfma_f32_16x16x32_bf16(                   \
            af[i], bfv[j], acc[i][j], 0, 0, 0);                                \
    __builtin_amdgcn_s_setprio(0);                                             \
  }

  STAGE4(0, 0);

  const int NTK = K >> 6;                        // 64 tiles, full K per block
#pragma unroll 1
  for (int t = 0; t < NTK - 1; ++t) {
    const int cb = t & 1, nb = cb ^ 1;
    STAGE4(nb, (t + 1) << 6);
    asm volatile("s_waitcnt vmcnt(4)" ::: "memory");
    __builtin_amdgcn_s_barrier();
    __builtin_amdgcn_sched_barrier(0);
    HALFK(cb, gx0);
    HALFK(cb, gx1);
    __builtin_amdgcn_s_barrier();
  }
  {
    const int cb = (NTK - 1) & 1;
    asm volatile("s_waitcnt vmcnt(0)" ::: "memory");
    __builtin_amdgcn_s_barrier();
    __builtin_amdgcn_sched_barrier(0);
    HALFK(cb, gx0);
    HALFK(cb, gx1);
  }
#undef STAGE4
#undef HALFK

  // owner epilogue: out += acc (each element written by exactly one block)
#pragma unroll
  for (int i = 0; i < 4; ++i) {
    const int row0 = bm + wrow + 16 * i + quad * 4;
#pragma unroll
    for (int j = 0; j < 2; ++j) {
      const int col = bn + wcol + 16 * j + lrow;
#pragma unroll
      for (int r = 0; r < 4; ++r) {
        float* p = &Cout[(size_t)(row0 + r) * N + col];
        *p = *p + acc[i][j][r];
      }
    }
  }
}

extern "C" void kernel_launch(void* const* d_in, const int* in_sizes, int n_in,
                              void* d_out, int out_size, void* d_ws, size_t ws_size,
                              hipStream_t stream) {
  const float* x      = (const float*)d_in[0];
  const int*   adj    = (const int*)d_in[1];
  const float* stoich = (const float*)d_in[2];
  const float* ln1g   = (const float*)d_in[3];
  const float* ln1b   = (const float*)d_in[4];
  const float* ln2g   = (const float*)d_in[5];
  const float* ln2b   = (const float*)d_in[6];
  const float* W1     = (const float*)d_in[7];
  const float* b1     = (const float*)d_in[8];
  const float* W2     = (const float*)d_in[9];
  const float* b2     = (const float*)d_in[10];
  const float* gW     = (const float*)d_in[11];
  const float* gb     = (const float*)d_in[12];
  float* out = (float*)d_out;
  char* ws = (char*)d_ws;

  ushort_t* normedB = (ushort_t*)(ws);                      //  8 MB (bf16)
  ushort_t* normed2 = (ushort_t*)(ws + (16u << 20));        //  8 MB
  ushort_t* hidden  = (ushort_t*)(ws + (24u << 20));        // 32 MB
  ushort_t* W1t     = (ushort_t*)(ws + (56u << 20));        //  8 MB
  ushort_t* W2t     = (ushort_t*)(ws + (64u << 20));        //  8 MB

  const int ROWS = BATCH * NTOK;  // 4096

  // merged LN1 + both weight transposes (LN blocks first)
  prep_kernel<<<12288, 256, 0, stream>>>(x, ln1g, ln1b, normedB,
                                         W1, W1t, W2, W2t);
  attn_kernel<<<ROWS / 2, 256, 0, stream>>>(x, normedB, adj, stoich, gW, gb,
                                            ln2g, ln2b, b2, out, normed2);
  // hidden(bf16) = gelu(normed2 @ W1 + b1): M=4096 N=4096 K=1024
  gemm1_pipe<<<1024, 512, 0, stream>>>(normed2, W1t, b1, hidden,
                                       ROWS, 4096, 1024);
  // out += hidden @ W2 (split-K=1, owner writes, no atomics): M=4096 N=1024 K=4096
  gemm2_pipe<<<256, 512, 0, stream>>>(hidden, W2t, out,
                                      ROWS, 1024, 4096);
}

// Round 15
// 251.928 us; speedup vs baseline: 1.0615x; 1.0615x over previous
//
#include <hip/hip_runtime.h>
#include <math.h>

#define NTOK 1024
#define DMODEL 1024
#define BATCH 4

typedef __bf16 bf16x8 __attribute__((ext_vector_type(8)));
typedef float  f32x4  __attribute__((ext_vector_type(4)));
typedef unsigned short ushort_t;
typedef unsigned short us8 __attribute__((ext_vector_type(8)));

static __device__ __forceinline__ ushort_t f2bf(float f) {
  unsigned u = __float_as_uint(f);
  u += 0x7fffu + ((u >> 16) & 1u);   // RNE (inputs are finite)
  return (ushort_t)(u >> 16);
}
static __device__ __forceinline__ float bf2f(ushort_t v) {
  return __uint_as_float(((unsigned)v) << 16);
}

// tanh-form gelu via sigmoid: gelu(v) = v * sigmoid(1.5957691·(v + 0.044715·v^3))
static __device__ __forceinline__ float fast_gelu(float v) {
  const float u = 1.5957691216057308f * (v + 0.044715f * v * v * v);
  return v / (1.f + __expf(-u));
}

static __device__ __forceinline__ void gld16(void* lds, const void* g) {
  __builtin_amdgcn_global_load_lds(
      (const __attribute__((address_space(1))) void*)g,
      (__attribute__((address_space(3))) void*)lds, 16, 0, 0);
}

// ---- merged prep: LN1 (blocks [0,4096)) + weight transposes ([4096,12288)) ----
__global__ __launch_bounds__(256) void prep_kernel(
    const float* __restrict__ x, const float* __restrict__ g,
    const float* __restrict__ b, ushort_t* __restrict__ out,
    const float* __restrict__ W1, ushort_t* __restrict__ W1t,
    const float* __restrict__ W2, ushort_t* __restrict__ W2t)
{
  if (blockIdx.x < 4096) {
    const int row = blockIdx.x;
    const int tid = threadIdx.x;
    const float* xr = x + (size_t)row * DMODEL;
    float4 v = *(const float4*)(xr + 4 * tid);
    float s1 = v.x + v.y + v.z + v.w;
    float s2 = v.x * v.x + v.y * v.y + v.z * v.z + v.w * v.w;
#pragma unroll
    for (int d = 1; d < 64; d <<= 1) { s1 += __shfl_xor(s1, d); s2 += __shfl_xor(s2, d); }
    __shared__ float red[10];
    const int wid = tid >> 6;
    if ((tid & 63) == 0) { red[wid] = s1; red[4 + wid] = s2; }
    __syncthreads();
    if (tid == 0) {
      float a = red[0] + red[1] + red[2] + red[3];
      float c = red[4] + red[5] + red[6] + red[7];
      float mu = a / (float)DMODEL;
      float var = c / (float)DMODEL - mu * mu;
      red[8] = mu; red[9] = rsqrtf(var + 1e-5f);
    }
    __syncthreads();
    const float mu = red[8], inv = red[9];
    float4 gg = *(const float4*)(g + 4 * tid);
    float4 bb = *(const float4*)(b + 4 * tid);
    ushort4 o;
    o.x = f2bf((v.x - mu) * inv * gg.x + bb.x);
    o.y = f2bf((v.y - mu) * inv * gg.y + bb.y);
    o.z = f2bf((v.z - mu) * inv * gg.z + bb.z);
    o.w = f2bf((v.w - mu) * inv * gg.w + bb.w);
    *(ushort4*)(out + (size_t)row * DMODEL + 4 * tid) = o;
  } else {
    __shared__ float t[32][33];
    int id = blockIdx.x - 4096;
    const float* W; ushort_t* Wt; int K, N, bx, by;
    if (id < 4096) { W = W1; Wt = W1t; K = 1024; N = 4096; bx = id & 127; by = id >> 7; }
    else { id -= 4096; W = W2; Wt = W2t; K = 4096; N = 1024; bx = id & 31; by = id >> 5; }
    const int kb = by * 32, nb = bx * 32;
    const int c = threadIdx.x & 31, r0 = threadIdx.x >> 5;
#pragma unroll
    for (int r = r0; r < 32; r += 8)
      t[r][c] = W[(size_t)(kb + r) * N + nb + c];
    __syncthreads();
#pragma unroll
    for (int r = r0; r < 32; r += 8)
      Wt[(size_t)(nb + r) * K + kb + c] = f2bf(t[c][r]);
  }
}

// ---- Sparse gated attention (bf16 K/V, 2 queries/block) + residual + LN2 ---
__global__ __launch_bounds__(256) void attn_kernel(
    const float* __restrict__ x, const ushort_t* __restrict__ normedB,
    const int* __restrict__ adj, const float* __restrict__ stoich,
    const float* __restrict__ gW, const float* __restrict__ gb,
    const float* __restrict__ ln2g, const float* __restrict__ ln2b,
    const float* __restrict__ b2,
    float* __restrict__ outbase, ushort_t* __restrict__ normed2)
{
  __shared__ int   neigh[2][NTOK];
  __shared__ float gateS[2][NTOK];
  __shared__ int   cntS[2];
  __shared__ float red[2][6];

  const int tid = threadIdx.x;
  const int sub = tid >> 7;
  const int t   = tid & 127;
  const int row = blockIdx.x * 2 + sub;   // [0, 4096)
  const int b   = row >> 10;

  if (tid < 2) cntS[tid] = 0;
  __syncthreads();
  const int* arow = adj + (size_t)row * NTOK;
  {
    int4 a4 = ((const int4*)arow)[t];
    int k0 = 4 * t;
    if (a4.x > 0) { int p = atomicAdd(&cntS[sub], 1); neigh[sub][p] = k0; }
    if (a4.y > 0) { int p = atomicAdd(&cntS[sub], 1); neigh[sub][p] = k0 + 1; }
    if (a4.z > 0) { int p = atomicAdd(&cntS[sub], 1); neigh[sub][p] = k0 + 2; }
    if (a4.w > 0) { int p = atomicAdd(&cntS[sub], 1); neigh[sub][p] = k0 + 3; }
    a4 = ((const int4*)arow)[t + 128];
    k0 = 4 * (t + 128);
    if (a4.x > 0) { int p = atomicAdd(&cntS[sub], 1); neigh[sub][p] = k0; }
    if (a4.y > 0) { int p = atomicAdd(&cntS[sub], 1); neigh[sub][p] = k0 + 1; }
    if (a4.z > 0) { int p = atomicAdd(&cntS[sub], 1); neigh[sub][p] = k0 + 2; }
    if (a4.w > 0) { int p = atomicAdd(&cntS[sub], 1); neigh[sub][p] = k0 + 3; }
  }
  __syncthreads();
  const int cnt = cntS[sub];

  const float st = stoich[row];
  for (int i = t; i < cnt; i += 128) {
    int k = neigh[sub][i];
    gateS[sub][i] = 1.f / (1.f + __expf(-fmaf(st, gW[k], gb[k])));
  }
  __syncthreads();

  const ushort_t* nbB = normedB + (size_t)b * NTOK * DMODEL;
  const int d0 = 8 * t;
  us8 qu = *(const us8*)(nbB + (size_t)(row & 1023) * DMODEL + d0);
  float qv[8];
#pragma unroll
  for (int j = 0; j < 8; ++j) qv[j] = bf2f(qu[j]);
  const float scale = 0.08838834764831845f;  // 1/sqrt(128)

  float lsum = 0.f;
  float o[8] = {0.f, 0.f, 0.f, 0.f, 0.f, 0.f, 0.f, 0.f};

  for (int i0 = 0; i0 < cnt; i0 += 8) {
    us8 ku[8]; float w8[8];
#pragma unroll
    for (int u = 0; u < 8; ++u) {
      const int i = i0 + u;
      const int ii = (i < cnt) ? i : 0;
      ku[u] = *(const us8*)(nbB + (size_t)neigh[sub][ii] * DMODEL + d0);
      w8[u] = gateS[sub][ii];
    }
#pragma unroll
    for (int u = 0; u < 8; ++u) {
      float p = 0.f;
#pragma unroll
      for (int j = 0; j < 8; ++j) p = fmaf(bf2f(ku[u][j]), qv[j], p);
      p += __shfl_xor(p, 1); p += __shfl_xor(p, 2);
      p += __shfl_xor(p, 4); p += __shfl_xor(p, 8);   // 16-lane head reduce
      w8[u] *= p * scale;
    }
#pragma unroll
    for (int u = 0; u < 8; ++u)
      w8[u] = (i0 + u < cnt) ? __expf(w8[u]) : 0.f;
#pragma unroll
    for (int u = 0; u < 8; ++u) {
      lsum += w8[u];
#pragma unroll
      for (int j = 0; j < 8; ++j) o[j] = fmaf(w8[u], bf2f(ku[u][j]), o[j]);
    }
  }
  const float pinv = 1.f / lsum;

  const float* xr = x + (size_t)row * DMODEL + d0;
  const float4 xa = *(const float4*)(xr);
  const float4 xb = *(const float4*)(xr + 4);
  float r[8];
  r[0] = xa.x + o[0] * pinv; r[1] = xa.y + o[1] * pinv;
  r[2] = xa.z + o[2] * pinv; r[3] = xa.w + o[3] * pinv;
  r[4] = xb.x + o[4] * pinv; r[5] = xb.y + o[5] * pinv;
  r[6] = xb.z + o[6] * pinv; r[7] = xb.w + o[7] * pinv;

  const float4 ba = *(const float4*)(b2 + d0);
  const float4 bbv = *(const float4*)(b2 + d0 + 4);
  float4 oa, ob;
  oa.x = r[0] + ba.x;  oa.y = r[1] + ba.y;  oa.z = r[2] + ba.z;  oa.w = r[3] + ba.w;
  ob.x = r[4] + bbv.x; ob.y = r[5] + bbv.y; ob.z = r[6] + bbv.z; ob.w = r[7] + bbv.w;
  float* obp = outbase + (size_t)row * DMODEL + d0;
  *(float4*)(obp) = oa;
  *(float4*)(obp + 4) = ob;

  float s1 = 0.f, s2 = 0.f;
#pragma unroll
  for (int j = 0; j < 8; ++j) { s1 += r[j]; s2 += r[j] * r[j]; }
#pragma unroll
  for (int d = 1; d < 64; d <<= 1) { s1 += __shfl_xor(s1, d); s2 += __shfl_xor(s2, d); }
  const int wsub = (tid >> 6) & 1;
  if ((tid & 63) == 0) { red[sub][wsub] = s1; red[sub][2 + wsub] = s2; }
  __syncthreads();
  if ((tid & 127) == 0) {
    float a = red[sub][0] + red[sub][1];
    float c = red[sub][2] + red[sub][3];
    float mu = a / (float)DMODEL;
    float var = c / (float)DMODEL - mu * mu;
    red[sub][4] = mu; red[sub][5] = rsqrtf(var + 1e-5f);
  }
  __syncthreads();
  const float mu = red[sub][4], inv = red[sub][5];
  const float4 ga = *(const float4*)(ln2g + d0);
  const float4 gbv = *(const float4*)(ln2g + d0 + 4);
  const float4 la = *(const float4*)(ln2b + d0);
  const float4 lb = *(const float4*)(ln2b + d0 + 4);
  const float gg[8] = {ga.x, ga.y, ga.z, ga.w, gbv.x, gbv.y, gbv.z, gbv.w};
  const float ll[8] = {la.x, la.y, la.z, la.w, lb.x, lb.y, lb.z, lb.w};
  us8 pk;
#pragma unroll
  for (int j = 0; j < 8; ++j) pk[j] = f2bf((r[j] - mu) * inv * gg[j] + ll[j]);
  *(us8*)(normed2 + (size_t)row * DMODEL + d0) = pk;
}

// ------- GEMM1 v3: 128x128 tile, 8 waves, 2 blocks/CU (r13 harness-passed) --
__global__ __launch_bounds__(512, 2) void gemm1_pipe(
    const ushort_t* __restrict__ A, const ushort_t* __restrict__ Bt,
    const float* __restrict__ bias, ushort_t* __restrict__ Cout,
    int M, int N, int K)
{
  __shared__ __align__(16) ushort_t As[2][128 * 64];
  __shared__ __align__(16) ushort_t Bs[2][128 * 64];

  const int id = blockIdx.x;
  const int xcd = id & 7, slot = id >> 3;        // slot 0..127
  const int bm = (xcd * 4 + (slot & 3)) * 128;   // 32 bm groups
  const int bn = (slot >> 2) * 128;              // 32 bn groups

  const int tid = threadIdx.x;                   // 0..511
  const int l = tid & 63;
  const int wid = tid >> 6;                      // 8 waves: 2(M) x 4(N)
  const int wrow = (wid >> 2) * 64;
  const int wcol = (wid & 3) * 32;

  const int sr = tid >> 3;                       // 0..63 within chunk
  const int sg = tid & 7;
  const int gsrc = ((sg ^ (sr & 7)) << 3);       // inverse-swizzled source granule
  const ushort_t* Ag = A  + (size_t)(bm + sr) * K + gsrc;
  const ushort_t* Bg = Bt + (size_t)(bn + sr) * K + gsrc;
  const int dst = tid * 8;

  const int quad = l >> 4, lrow = l & 15;
  const int swz = lrow & 7;
  const int gx0 = ((quad ^ swz) << 3);
  const int gx1 = (((quad + 4) ^ swz) << 3);

  f32x4 acc[4][2] = {};

#define STAGE4(buf, kb)                                                        \
  gld16(&As[buf][dst],        Ag + (kb));                                      \
  gld16(&As[buf][4096 + dst], Ag + (size_t)64 * K + (kb));                     \
  gld16(&Bs[buf][dst],        Bg + (kb));                                      \
  gld16(&Bs[buf][4096 + dst], Bg + (size_t)64 * K + (kb));

#define HALFK(buf, GX)                                                         \
  {                                                                            \
    bf16x8 af[4], bfv[2];                                                      \
    _Pragma("unroll")                                                          \
    for (int i = 0; i < 4; ++i)                                                \
      af[i] = *(const bf16x8*)(&As[buf][(wrow + i * 16 + lrow) * 64 + (GX)]);  \
    _Pragma("unroll")                                                          \
    for (int j = 0; j < 2; ++j)                                                \
      bfv[j] = *(const bf16x8*)(&Bs[buf][(wcol + j * 16 + lrow) * 64 + (GX)]); \
    __builtin_amdgcn_s_setprio(1);                                             \
    _Pragma("unroll")                                                          \
    for (int i = 0; i < 4; ++i)                                                \
      _Pragma("unroll")                                                        \
      for (int j = 0; j < 2; ++j)                                              \
        acc[i][j] = __builtin_amdgcn_mfma_f32_16x16x32_bf16(                   \
            af[i], bfv[j], acc[i][j], 0, 0, 0);                                \
    __builtin_amdgcn_s_setprio(0);                                             \
  }

  STAGE4(0, 0);

  const int NTK = K >> 6;                        // 16 K-tiles
#pragma unroll 1
  for (int t = 0; t < NTK - 1; ++t) {
    const int cb = t & 1, nb = cb ^ 1;
    STAGE4(nb, (t + 1) << 6);
    asm volatile("s_waitcnt vmcnt(4)" ::: "memory");
    __builtin_amdgcn_s_barrier();
    __builtin_amdgcn_sched_barrier(0);
    HALFK(cb, gx0);
    HALFK(cb, gx1);
    __builtin_amdgcn_s_barrier();
  }
  {
    const int cb = (NTK - 1) & 1;
    asm volatile("s_waitcnt vmcnt(0)" ::: "memory");
    __builtin_amdgcn_s_barrier();
    __builtin_amdgcn_sched_barrier(0);
    HALFK(cb, gx0);
    HALFK(cb, gx1);
  }
#undef STAGE4
#undef HALFK

  // epilogue: gelu(acc + bias) -> bf16
#pragma unroll
  for (int i = 0; i < 4; ++i) {
    const int row0 = bm + wrow + 16 * i + quad * 4;
#pragma unroll
    for (int j = 0; j < 2; ++j) {
      const int col = bn + wcol + 16 * j + lrow;
      const float bi = bias[col];
#pragma unroll
      for (int r = 0; r < 4; ++r)
        Cout[(size_t)(row0 + r) * N + col] = f2bf(fast_gelu(acc[i][j][r] + bi));
    }
  }
}

// ------- GEMM2 v4: 64x128 tile, 8 waves, full-K owner-writes, 2 blocks/CU ---
// r11-r13 three-point comparison: v2 (splitK2+atomics, 2 blk/CU) 62us;
// v3 (no atomics, 1 blk/CU) 72us — cross-block TLP dominates epilogue cost
// (m114). v4 combines both levers: grid (M/64)x(N/128) = 64x8 = 512 blocks
// = 2/CU, each block owns full K -> plain owner read-add-store, no atomics.
// Same verified skeleton: STAGE 3 gld16/thread -> vmcnt(3), 2 barriers,
// both-sides granule swizzle. LDS 48KB (A 16 + B 32, dbuf). 8 waves 2Mx4N,
// per-wave 32x32 (acc[2][2]).
__global__ __launch_bounds__(512, 2) void gemm2_pipe(
    const ushort_t* __restrict__ A, const ushort_t* __restrict__ Bt,
    float* __restrict__ Cout, int M, int N, int K)
{
  __shared__ __align__(16) ushort_t As[2][64 * 64];
  __shared__ __align__(16) ushort_t Bs[2][128 * 64];

  const int id = blockIdx.x;
  const int xcd = id & 7, slot = id >> 3;        // slot 0..63
  const int bm = (xcd * 8 + (slot & 7)) * 64;    // 64 bm groups
  const int bn = (slot >> 3) * 128;              // 8 bn groups

  const int tid = threadIdx.x;                   // 0..511
  const int l = tid & 63;
  const int wid = tid >> 6;                      // 8 waves: 2(M) x 4(N)
  const int wrow = (wid >> 2) * 32;
  const int wcol = (wid & 3) * 32;

  const int sr = tid >> 3;                       // 0..63 within chunk
  const int sg = tid & 7;
  const int gsrc = ((sg ^ (sr & 7)) << 3);
  const ushort_t* Ag = A  + (size_t)(bm + sr) * K + gsrc;
  const ushort_t* Bg = Bt + (size_t)(bn + sr) * K + gsrc;
  const int dst = tid * 8;

  const int quad = l >> 4, lrow = l & 15;
  const int swz = lrow & 7;
  const int gx0 = ((quad ^ swz) << 3);
  const int gx1 = (((quad + 4) ^ swz) << 3);

  f32x4 acc[2][2] = {};

#define STAGE3(buf, kb)                                                        \
  gld16(&As[buf][dst],        Ag + (kb));                                      \
  gld16(&Bs[buf][dst],        Bg + (kb));                                      \
  gld16(&Bs[buf][4096 + dst], Bg + (size_t)64 * K + (kb));

#define HALFK(buf, GX)                                                         \
  {                                                                            \
    bf16x8 af[2], bfv[2];                                                      \
    _Pragma("unroll")                                                          \
    for (int i = 0; i < 2; ++i)                                                \
      af[i] = *(const bf16x8*)(&As[buf][(wrow + i * 16 + lrow) * 64 + (GX)]);  \
    _Pragma("unroll")                                                          \
    for (int j = 0; j < 2; ++j)                                                \
      bfv[j] = *(const bf16x8*)(&Bs[buf][(wcol + j * 16 + lrow) * 64 + (GX)]); \
    __builtin_amdgcn_s_setprio(1);                                             \
    _Pragma("unroll")                                                          \
    for (int i = 0; i < 2; ++i)                                                \
      _Pragma("unroll")                                                        \
      for (int j = 0; j < 2; ++j)                                              \
        acc[i][j] = __builtin_amdgcn_mfma_f32_16x16x32_bf16(                   \
            af[i], bfv[j], acc[i][j], 0, 0, 0);                                \
    __builtin_amdgcn_s_setprio(0);                                             \
  }

  STAGE3(0, 0);

  const int NTK = K >> 6;                        // 64 tiles, full K per block
#pragma unroll 1
  for (int t = 0; t < NTK - 1; ++t) {
    const int cb = t & 1, nb = cb ^ 1;
    STAGE3(nb, (t + 1) << 6);
    asm volatile("s_waitcnt vmcnt(3)" ::: "memory");
    __builtin_amdgcn_s_barrier();
    __builtin_amdgcn_sched_barrier(0);
    HALFK(cb, gx0);
    HALFK(cb, gx1);
    __builtin_amdgcn_s_barrier();
  }
  {
    const int cb = (NTK - 1) & 1;
    asm volatile("s_waitcnt vmcnt(0)" ::: "memory");
    __builtin_amdgcn_s_barrier();
    __builtin_amdgcn_sched_barrier(0);
    HALFK(cb, gx0);
    HALFK(cb, gx1);
  }
#undef STAGE3
#undef HALFK

  // owner epilogue: out += acc (each element written by exactly one block)
#pragma unroll
  for (int i = 0; i < 2; ++i) {
    const int row0 = bm + wrow + 16 * i + quad * 4;
#pragma unroll
    for (int j = 0; j < 2; ++j) {
      const int col = bn + wcol + 16 * j + lrow;
#pragma unroll
      for (int r = 0; r < 4; ++r) {
        float* p = &Cout[(size_t)(row0 + r) * N + col];
        *p = *p + acc[i][j][r];
      }
    }
  }
}

extern "C" void kernel_launch(void* const* d_in, const int* in_sizes, int n_in,
                              void* d_out, int out_size, void* d_ws, size_t ws_size,
                              hipStream_t stream) {
  const float* x      = (const float*)d_in[0];
  const int*   adj    = (const int*)d_in[1];
  const float* stoich = (const float*)d_in[2];
  const float* ln1g   = (const float*)d_in[3];
  const float* ln1b   = (const float*)d_in[4];
  const float* ln2g   = (const float*)d_in[5];
  const float* ln2b   = (const float*)d_in[6];
  const float* W1     = (const float*)d_in[7];
  const float* b1     = (const float*)d_in[8];
  const float* W2     = (const float*)d_in[9];
  const float* b2     = (const float*)d_in[10];
  const float* gW     = (const float*)d_in[11];
  const float* gb     = (const float*)d_in[12];
  float* out = (float*)d_out;
  char* ws = (char*)d_ws;

  ushort_t* normedB = (ushort_t*)(ws);                      //  8 MB (bf16)
  ushort_t* normed2 = (ushort_t*)(ws + (16u << 20));        //  8 MB
  ushort_t* hidden  = (ushort_t*)(ws + (24u << 20));        // 32 MB
  ushort_t* W1t     = (ushort_t*)(ws + (56u << 20));        //  8 MB
  ushort_t* W2t     = (ushort_t*)(ws + (64u << 20));        //  8 MB

  const int ROWS = BATCH * NTOK;  // 4096

  // merged LN1 + both weight transposes (LN blocks first)
  prep_kernel<<<12288, 256, 0, stream>>>(x, ln1g, ln1b, normedB,
                                         W1, W1t, W2, W2t);
  attn_kernel<<<ROWS / 2, 256, 0, stream>>>(x, normedB, adj, stoich, gW, gb,
                                            ln2g, ln2b, b2, out, normed2);
  // hidden(bf16) = gelu(normed2 @ W1 + b1): M=4096 N=4096 K=1024
  gemm1_pipe<<<1024, 512, 0, stream>>>(normed2, W1t, b1, hidden,
                                       ROWS, 4096, 1024);
  // out += hidden @ W2 (64x128 tile, full-K owner writes): M=4096 N=1024 K=4096
  gemm2_pipe<<<512, 512, 0, stream>>>(hidden, W2t, out,
                                      ROWS, 1024, 4096);
}